// Round 6
// baseline (209.736 us; speedup 1.0000x reference)
//
#include <hip/hip_runtime.h>
#include <hip/hip_bf16.h>
#include <stdint.h>

// KAN layer fused kernel, MI355X (gfx950) — V7: phase-split, arch-reg-budgeted.
// out[M=65536, N=256] (fp32) = A[M, K=256] @ W^T, where
//   A[m,k] = c0[k]*B0(tanh(x[m,k])) + c1[k]*B1(tanh(x[m,k]))  (on the fly -> bf16)
//   W = outer_coeffs [N,K] fp32 -> bf16 (conv_w, SWIZZLED layout, into d_ws)
//   conv_w also packs C2g[256] = (ic[k][0], ic[k][1]) at d_ws+131072.
//
// Allocator model (from V1/V3/V5/V6 counters): VGPR_Count = ARCH side only;
// with MFMA accumulators in AGPRs the allocator splits the unified file and
// will NOT take the arch side past 128 (spills instead), regardless of
// launch_bounds' 256 budget. => RULE: arch live-set <= ~110 at every point.
// Ladder: V1 58 (per-K barriers) V2 87 (reg serialization) V3 44 (clean, arch~48)
//   V4 181 / V5 119 / V6 119 (phase-split spills: xv[16]+af = ~135 arch > 128).
// V7 = V6 with x in HALF-strips (8 float4 = 32 regs): peaks ~106/100 arch.
//  - x0.halfA pre-DMA; x0.halfB post-DMA (its wait comes after spline-h0, by
//    which time the L2-hot DMA has drained anyway — no added stall);
//  - x1.halfA before MFMA sweep 0; x1.halfB before stores (vmcnt in-order);
//  - B-frags in groups of 4 (16 transient regs); setprio(1) around MFMA
//    clusters (2 anti-phased waves/SIMD); single __syncthreads after spline-0.

typedef __attribute__((ext_vector_type(8))) short short8;   // 8 bf16 = 4 VGPR (MFMA A/B frag)
typedef __attribute__((ext_vector_type(4))) float f32x4;    // MFMA C/D frag

__device__ __forceinline__ uint16_t f2bf(float f) {
    union { float f; uint32_t u; } v; v.f = f;
    uint32_t r = v.u + 0x7FFFu + ((v.u >> 16) & 1u);  // RNE
    return (uint16_t)(r >> 16);
}

// Pack 2 floats -> 2 bf16 (RNE) in one v_cvt_pk_bf16_f32 (compiler-emitted)
__device__ __forceinline__ uint32_t pack_bf2(float lo, float hi) {
    __hip_bfloat162 h = __float22bfloat162_rn(make_float2(lo, hi));
    union { __hip_bfloat162 h; uint32_t u; } v; v.h = h;
    return v.u;
}

__device__ __forceinline__ float cube_relu(float v) {
    float m = fmaxf(v, 0.0f);
    return m * m * m;
}

__device__ __forceinline__ float inner_eval(float xx, float c0, float c1) {
    // tanh via exp: tanh(x) = 1 - 2/(e^{2x}+1); saturates correctly at +/-inf
    float e  = __expf(2.0f * xx);
    float t  = 1.0f - 2.0f * __builtin_amdgcn_rcpf(e + 1.0f);
    float u  = (t + 1.0f) * 3.5f;          // in [0,7]
    float w0 = cube_relu(u);
    float w1 = cube_relu(u - 1.0f);
    float w2 = cube_relu(u - 2.0f);
    float w3 = cube_relu(u - 3.0f);
    float w4 = cube_relu(u - 4.0f);
    float w5 = cube_relu(u - 5.0f);
    float B0 = w0 - 4.0f*w1 + 6.0f*w2 - 4.0f*w3 + w4;
    float B1 = w1 - 4.0f*w2 + 6.0f*w3 - 4.0f*w4 + w5;
    return (c0 * B0 + c1 * B1) * (1.0f / 6.0f);
}

__device__ __forceinline__ void load_lds16(const void* g, void* l) {
    __builtin_amdgcn_global_load_lds(
        (const __attribute__((address_space(1))) uint32_t*)g,
        (__attribute__((address_space(3))) uint32_t*)l, 16, 0, 0);
}

// W fp32 -> bf16 into the XOR-SWIZZLED layout kan_fused's ds_reads expect:
//   value W[row][col] lands at byte  row*512 + ((col*2) ^ ((row&7)<<4)).
// Also packs the (c0,c1) coeff table at offset 131072 (2 KB).
__global__ void conv_w(const float* __restrict__ ic, const float4* __restrict__ wf,
                       char* __restrict__ o) {
    const int i = blockIdx.x * blockDim.x + threadIdx.x;  // 0..16383
    const float4 v = wf[i];
    uint2 r;
    r.x = (uint32_t)f2bf(v.x) | ((uint32_t)f2bf(v.y) << 16);
    r.y = (uint32_t)f2bf(v.z) | ((uint32_t)f2bf(v.w) << 16);
    const int row = i >> 6;           // 64 threads per 256-float row
    const int cb  = (i & 63) << 3;    // byte col within row, 8-aligned
    *(uint2*)(o + row * 512 + (cb ^ ((row & 7) << 4))) = r;
    if (i < 256)
        *(float2*)(o + 131072 + i * 8) = make_float2(ic[i * 5 + 0], ic[i * 5 + 1]);
}

// A-fragment for one K-step: 8 inner_evals + pack to short8.
__device__ __forceinline__ short8 spline8(float4 xa, float4 xb, const float2* C2, int gk) {
    const float4 cA = *(const float4*)(&C2[gk + 0]);   // c0,c1 of ch gk, gk+1
    const float4 cB = *(const float4*)(&C2[gk + 2]);
    const float4 cC = *(const float4*)(&C2[gk + 4]);
    const float4 cD = *(const float4*)(&C2[gk + 6]);
    float v0 = inner_eval(xa.x, cA.x, cA.y);
    float v1 = inner_eval(xa.y, cA.z, cA.w);
    float v2 = inner_eval(xa.z, cB.x, cB.y);
    float v3 = inner_eval(xa.w, cB.z, cB.w);
    float v4 = inner_eval(xb.x, cC.x, cC.y);
    float v5 = inner_eval(xb.y, cC.z, cC.w);
    float v6 = inner_eval(xb.z, cD.x, cD.y);
    float v7 = inner_eval(xb.w, cD.z, cD.w);
    union { short8 v; uint32_t u[4]; } af;
    af.u[0] = pack_bf2(v0, v1);
    af.u[1] = pack_bf2(v2, v3);
    af.u[2] = pack_bf2(v4, v5);
    af.u[3] = pack_bf2(v6, v7);
    return af.v;
}

// Phase B: full-K MFMA sweep. 128 ds_read_b128 + 128 MFMA, b in groups of 4
// (16 transient arch regs), setprio around each MFMA cluster. acc -> AGPRs.
__device__ __forceinline__ void mfma_sweep(const short8* af, const char* Wlds,
                                           int mrow, int quad, int swz, f32x4* acc) {
    #pragma unroll
    for (int j = 0; j < 16; ++j) acc[j] = (f32x4){0.f, 0.f, 0.f, 0.f};

    #pragma unroll
    for (int kk = 0; kk < 8; ++kk) {
        const int cw = (kk * 64 + quad * 16) ^ swz;
        #pragma unroll
        for (int g = 0; g < 4; ++g) {
            short8 bg[4];
            #pragma unroll
            for (int j = 0; j < 4; ++j)
                bg[j] = *(const short8*)(Wlds + (((g * 4 + j) * 16 + mrow) << 9) + cw);
            __builtin_amdgcn_s_setprio(1);
            #pragma unroll
            for (int j = 0; j < 4; ++j)
                acc[g * 4 + j] = __builtin_amdgcn_mfma_f32_16x16x32_bf16(af[kk], bg[j], acc[g * 4 + j], 0, 0, 0);
            __builtin_amdgcn_s_setprio(0);
        }
    }
}

// Epilogue: fp32 stores; per inst 4 quad-rows x 64B contiguous segments.
__device__ __forceinline__ void store_acc(const f32x4* acc, float* __restrict__ out,
                                          int mbase, int mrow, int quad) {
    float* op = out + (size_t)(mbase + quad * 4) * 256 + mrow;
    #pragma unroll
    for (int j = 0; j < 16; ++j) {
        #pragma unroll
        for (int r = 0; r < 4; ++r)
            op[(size_t)r * 256 + j * 16] = acc[j][r];
    }
}

// Block: 512 threads = 8 waves, grid 256 -> 1 block/CU (LDS-limited, 2 waves/SIMD).
// Wave w handles strips w*16 and w*16+128; all 256 output cols (16 n-tiles).
// Lane mapping (verified V1-V6): mrow=lane&15, quad=lane>>4;
//   A frag: A[m=mrow][k=quad*8+i]; B frag: W[n=mrow][k=quad*8+i]; C/D: col=mrow, row=quad*4+r.
__global__ void __launch_bounds__(512, 2) kan_fused(const float* __restrict__ x,
                                                    const char* __restrict__ wb,
                                                    float* __restrict__ out)
{
    __shared__ __align__(16) char smem[133120];
    char*   Wlds = smem;                       // [256 rows][512 B], swizzled
    float2* C2   = (float2*)(smem + 131072);   // (c0,c1) per channel

    const int t    = threadIdx.x;
    const int lane = t & 63;
    const int w    = t >> 6;
    const int mrow = lane & 15;
    const int quad = lane >> 4;
    const int swz  = (mrow & 7) << 4;

    const int mb0 = blockIdx.x * 256 + w * 16;   // strip 0 rows
    const int mb1 = mb0 + 128;                   // strip 1 rows

    const float* xr0 = x + (size_t)(mb0 + mrow) * 256 + quad * 8;
    const float* xr1 = x + (size_t)(mb1 + mrow) * 256 + quad * 8;

    float4 xa[8], xb[8];   // HALF-strip x batches: 32 arch regs each

    // (1) strip-0 x, half A (kk 0..3): issued FIRST (pre-DMA -> its wait never
    //     forces the W DMA to drain)
    #pragma unroll
    for (int kk = 0; kk < 4; ++kk) {
        xa[2 * kk]     = *(const float4*)(xr0 + kk * 32);
        xa[2 * kk + 1] = *(const float4*)(xr0 + kk * 32 + 4);
    }

    // (2) coeff table from global (packed by conv_w; L2-hot); dies at step (4)
    const float4* c2g = (const float4*)(wb + 131072);
    const float4 cg0 = c2g[lane * 2];
    const float4 cg1 = c2g[lane * 2 + 1];

    // (3) W DMA: 128 KB linear, 16 rounds x 8 waves x 1 KB (L2-hot, ~2.3K cyc)
    #pragma unroll
    for (int it = 0; it < 16; ++it) {
        const int base = ((it * 8 + w) << 10) + lane * 16;
        load_lds16(wb + base, Wlds + base);
    }

    // (4) every wave writes the whole 2 KB C2 table (identical values: benign
    //     race; own-wave lgkm ordering makes it readable with NO barrier)
    *(float4*)((char*)C2 + lane * 32)      = cg0;
    *(float4*)((char*)C2 + lane * 32 + 16) = cg1;

    // (5) strip-0 x, half B: issued post-DMA. Its vmcnt wait (at spline h1)
    //     also drains the DMA — which spline h0 has covered by then.
    #pragma unroll
    for (int kk = 4; kk < 8; ++kk) {
        xb[2 * (kk - 4)]     = *(const float4*)(xr0 + kk * 32);
        xb[2 * (kk - 4) + 1] = *(const float4*)(xr0 + kk * 32 + 4);
    }

    // (6) spline strip-0 half A (pure VALU; xa dies into af)
    short8 af[8];
    #pragma unroll
    for (int kk = 0; kk < 4; ++kk)
        af[kk] = spline8(xa[2 * kk], xa[2 * kk + 1], C2, kk * 32 + quad * 8);

    // (7) spline strip-0 half B
    #pragma unroll
    for (int kk = 4; kk < 8; ++kk)
        af[kk] = spline8(xb[2 * (kk - 4)], xb[2 * (kk - 4) + 1], C2, kk * 32 + quad * 8);

    __syncthreads();   // the ONLY barrier: W staged (DMA drained under spline)

    // (8) strip-1 x, half A: in flight under the strip-0 MFMA sweep
    #pragma unroll
    for (int kk = 0; kk < 4; ++kk) {
        xa[2 * kk]     = *(const float4*)(xr1 + kk * 32);
        xa[2 * kk + 1] = *(const float4*)(xr1 + kk * 32 + 4);
    }

    // (9) phase B0: uninterrupted ds_read/MFMA sweep for strip 0
    f32x4 acc[16];
    mfma_sweep(af, Wlds, mrow, quad, swz, acc);

    // (10) strip-1 x, half B — BEFORE the stores (vmcnt retires in order;
    //      issued after stores they'd wait on store-acks)
    #pragma unroll
    for (int kk = 4; kk < 8; ++kk) {
        xb[2 * (kk - 4)]     = *(const float4*)(xr1 + kk * 32);
        xb[2 * (kk - 4) + 1] = *(const float4*)(xr1 + kk * 32 + 4);
    }

    // (11) epilogue strip 0 (fire-and-forget stores)
    store_acc(acc, out, mb0, mrow, quad);

    // (12) spline strip 1 (both halves; xa arrived under sweep 0, xb under stores)
    #pragma unroll
    for (int kk = 0; kk < 4; ++kk)
        af[kk] = spline8(xa[2 * kk], xa[2 * kk + 1], C2, kk * 32 + quad * 8);
    #pragma unroll
    for (int kk = 4; kk < 8; ++kk)
        af[kk] = spline8(xb[2 * (kk - 4)], xb[2 * (kk - 4) + 1], C2, kk * 32 + quad * 8);

    // (13) phase B1 + epilogue strip 1
    mfma_sweep(af, Wlds, mrow, quad, swz, acc);
    store_acc(acc, out, mb1, mrow, quad);
}

extern "C" void kernel_launch(void* const* d_in, const int* in_sizes, int n_in,
                              void* d_out, int out_size, void* d_ws, size_t ws_size,
                              hipStream_t stream) {
    const float* x  = (const float*)d_in[0];   // [16,4096,256] fp32
    const float* ic = (const float*)d_in[1];   // [256,5] fp32
    const float* oc = (const float*)d_in[2];   // [256,256] fp32
    char* wb = (char*)d_ws;                    // 128 KB swizzled W + 2 KB coeff table

    conv_w<<<64, 256, 0, stream>>>(ic, (const float4*)oc, wb);
    kan_fused<<<256, 512, 0, stream>>>(x, wb, (float*)d_out);
}

// Round 8
// 130.198 us; speedup vs baseline: 1.6109x; 1.6109x over previous
//
#include <hip/hip_runtime.h>
#include <hip/hip_bf16.h>
#include <stdint.h>

// KAN layer fused kernel, MI355X (gfx950) — V8: V3 streaming shape + 32x32x16 MFMA.
// out[M=65536, N=256] (fp32) = A[M, K=256] @ W^T, where
//   A[m,k] = c0[k]*B0(tanh(x[m,k])) + c1[k]*B1(tanh(x[m,k]))  (on the fly -> bf16)
//   W = outer_coeffs [N,K] fp32 -> bf16 (conv_w, SWIZZLED layout, into d_ws)
//
// Ladder: V1 58 (per-K barriers) V2 87 (global-B serialization) V3 44 (CLEAN:
//   whole-W LDS, streaming loop, VGPR 112, FETCH 33MB) V4/V5/V6/V7 119-181
//   (ALL phase-split variants spill: batching x/af across phases pins the arch
//   side at 128 and scratches ~150MB — allocator handles only the streaming
//   shape where each kk's values are produced and consumed in-loop).
// V8 = V3's exact streaming shape, but wave owns 32 rows x 256 cols using
//   mfma_f32_32x32x16_bf16 (8 n-tiles, acc = 8 x f32x16 = 128 AGPRs):
//   - B LDS traffic per block HALVES (2MB -> 1MB): each b128 read feeds a
//     32x32 tile instead of 16x16. One pass, no strip loop.
//   - per-iter: 8 ds_read_b128 + 8 MFMA + 8 inner_evals; 16 iters (k-step 16).
//   - arch live set ~100 (b[8]=32, x cur/next 16, af 4, temps) -> no spill.
// Mappings (guide-verified m74/m101 + V1-V3 HW-verified 16x16 analog):
//   A: m=lane&31, k=(lane>>5)*8+e;  B: n=lane&31, same k;
//   C/D: col=lane&31 (n), row=(r&3)+8*(r>>2)+4*(lane>>5) (m), r in [0,16).
// (Round 7 bench was an infra failure — container died; this is the same V8
//  resubmitted after an offline correctness re-audit found no defects.)

typedef __attribute__((ext_vector_type(8))) short short8;    // 8 bf16 = 4 VGPR (MFMA A/B frag)
typedef __attribute__((ext_vector_type(16))) float f32x16;   // 32x32 MFMA C/D frag

__device__ __forceinline__ uint16_t f2bf(float f) {
    union { float f; uint32_t u; } v; v.f = f;
    uint32_t r = v.u + 0x7FFFu + ((v.u >> 16) & 1u);  // RNE
    return (uint16_t)(r >> 16);
}

// Pack 2 floats -> 2 bf16 (RNE) in one v_cvt_pk_bf16_f32 (compiler-emitted)
__device__ __forceinline__ uint32_t pack_bf2(float lo, float hi) {
    __hip_bfloat162 h = __float22bfloat162_rn(make_float2(lo, hi));
    union { __hip_bfloat162 h; uint32_t u; } v; v.h = h;
    return v.u;
}

__device__ __forceinline__ float cube_relu(float v) {
    float m = fmaxf(v, 0.0f);
    return m * m * m;
}

__device__ __forceinline__ float inner_eval(float xx, float c0, float c1) {
    // tanh via exp: tanh(x) = 1 - 2/(e^{2x}+1); saturates correctly at +/-inf
    float e  = __expf(2.0f * xx);
    float t  = 1.0f - 2.0f * __builtin_amdgcn_rcpf(e + 1.0f);
    float u  = (t + 1.0f) * 3.5f;          // in [0,7]
    float w0 = cube_relu(u);
    float w1 = cube_relu(u - 1.0f);
    float w2 = cube_relu(u - 2.0f);
    float w3 = cube_relu(u - 3.0f);
    float w4 = cube_relu(u - 4.0f);
    float w5 = cube_relu(u - 5.0f);
    float B0 = w0 - 4.0f*w1 + 6.0f*w2 - 4.0f*w3 + w4;
    float B1 = w1 - 4.0f*w2 + 6.0f*w3 - 4.0f*w4 + w5;
    return (c0 * B0 + c1 * B1) * (1.0f / 6.0f);
}

__device__ __forceinline__ void load_lds16(const void* g, void* l) {
    __builtin_amdgcn_global_load_lds(
        (const __attribute__((address_space(1))) uint32_t*)g,
        (__attribute__((address_space(3))) uint32_t*)l, 16, 0, 0);
}

// W fp32 -> bf16 into the XOR-SWIZZLED layout kan_fused's ds_reads expect:
//   value W[row][col] lands at byte  row*512 + ((col*2) ^ ((row&7)<<4)).
// Thread i covers floats 4i..4i+3 = one 8-byte bf16 chunk (col*2 is 8-aligned;
// XOR touches bits 4..6 only, so the chunk stays 8-aligned and contiguous).
__global__ void conv_w(const float4* __restrict__ wf, char* __restrict__ o) {
    const int i = blockIdx.x * blockDim.x + threadIdx.x;  // 0..16383
    const float4 v = wf[i];
    uint2 r;
    r.x = (uint32_t)f2bf(v.x) | ((uint32_t)f2bf(v.y) << 16);
    r.y = (uint32_t)f2bf(v.z) | ((uint32_t)f2bf(v.w) << 16);
    const int row = i >> 6;           // 64 threads per 256-float row
    const int cb  = (i & 63) << 3;    // byte col within row, 8-aligned
    *(uint2*)(o + row * 512 + (cb ^ ((row & 7) << 4))) = r;
}

// Block: 512 threads = 8 waves, grid 256 -> 1 block/CU (LDS-limited, 2 waves/SIMD).
// Wave w owns rows [bid*256 + w*32, +32), all 256 cols as 8 n-tiles of 32x32.
__global__ void __launch_bounds__(512, 2) kan_fused(const float* __restrict__ x,
                                                    const float* __restrict__ ic,
                                                    const char* __restrict__ wb,
                                                    float* __restrict__ out)
{
    __shared__ __align__(16) char smem[133120];
    char*   Wlds = smem;                       // [256 rows][512 B], swizzled
    float2* C2   = (float2*)(smem + 131072);   // (c0,c1) per channel

    const int t    = threadIdx.x;
    const int lane = t & 63;
    const int w    = t >> 6;
    const int col  = lane & 31;     // A row-in-strip / B n-in-tile / C col
    const int half = lane >> 5;     // k-half selector (8 k each)
    const int swz  = (col & 7) << 4;

    const int mb = blockIdx.x * 256 + w * 32;   // wave's first output row
    const float* xp = x + (size_t)(mb + col) * 256 + half * 8;

    // x for kk=0, issued FIRST (pre-DMA: in-order vmcnt means its wait never
    // forces the W DMA to drain; barrier covers completeness anyway)
    float4 xa = *(const float4*)(xp);
    float4 xb = *(const float4*)(xp + 4);

    // coeff table (tiny, L2-hot)
    if (t < 256) C2[t] = make_float2(ic[t * 5 + 0], ic[t * 5 + 1]);

    // Stage all 128 KB of (pre-swizzled) W linearly: 16 issues x 8 waves x 1 KB.
    #pragma unroll
    for (int it = 0; it < 16; ++it) {
        const int base = ((it * 8 + w) << 10) + lane * 16;
        load_lds16(wb + base, Wlds + base);
    }
    __syncthreads();   // the ONLY barrier: W staged + C2 visible

    f32x16 acc[8];
    #pragma unroll
    for (int j = 0; j < 8; ++j)
        #pragma unroll
        for (int r = 0; r < 16; ++r)
            acc[j][r] = 0.0f;

    #pragma unroll 1
    for (int kk = 0; kk < 16; ++kk) {
        // --- B frags from LDS (swizzled): tile j -> row j*32+col, k-half chunk ---
        const int cw = (kk * 32 + half * 16) ^ swz;
        short8 b[8];
        #pragma unroll
        for (int j = 0; j < 8; ++j)
            b[j] = *(const short8*)(Wlds + ((j * 32 + col) << 9) + cw);

        // --- next-iter x prefetch (hides L3/HBM latency under spline VALU) ---
        float4 xa_n = xa, xb_n = xb;
        if (kk < 15) {
            xa_n = *(const float4*)(xp + (kk + 1) * 16);
            xb_n = *(const float4*)(xp + (kk + 1) * 16 + 4);
        }

        // --- coeffs for this lane's 8 channels (LDS broadcast) ---
        const int gk = kk * 16 + half * 8;
        const float4 cA = *(const float4*)(&C2[gk + 0]);
        const float4 cB = *(const float4*)(&C2[gk + 2]);
        const float4 cC = *(const float4*)(&C2[gk + 4]);
        const float4 cD = *(const float4*)(&C2[gk + 6]);

        // --- spline VALU block: A[m = mb+col][k = kk*16 + half*8 + 0..7] ---
        float v0 = inner_eval(xa.x, cA.x, cA.y);
        float v1 = inner_eval(xa.y, cA.z, cA.w);
        float v2 = inner_eval(xa.z, cB.x, cB.y);
        float v3 = inner_eval(xa.w, cB.z, cB.w);
        float v4 = inner_eval(xb.x, cC.x, cC.y);
        float v5 = inner_eval(xb.y, cC.z, cC.w);
        float v6 = inner_eval(xb.z, cD.x, cD.y);
        float v7 = inner_eval(xb.w, cD.z, cD.w);

        union { short8 v; uint32_t u[4]; } af;
        af.u[0] = pack_bf2(v0, v1);
        af.u[1] = pack_bf2(v2, v3);
        af.u[2] = pack_bf2(v4, v5);
        af.u[3] = pack_bf2(v6, v7);

        // --- MFMA sweep: 8 x 32x32x16 (independent acc chains) ---
        #pragma unroll
        for (int j = 0; j < 8; ++j)
            acc[j] = __builtin_amdgcn_mfma_f32_32x32x16_bf16(af.v, b[j], acc[j], 0, 0, 0);

        xa = xa_n; xb = xb_n;
    }

    // --- epilogue: C/D layout col=lane&31, row=(r&3)+8*(r>>2)+4*half ---
    // Per (j,r) store inst: two 128B contiguous row segments (one per half).
    float* op = out + (size_t)(mb + 4 * half) * 256 + col;
    #pragma unroll
    for (int j = 0; j < 8; ++j) {
        #pragma unroll
        for (int r = 0; r < 16; ++r)
            op[(size_t)((r & 3) + 8 * (r >> 2)) * 256 + j * 32] = acc[j][r];
    }
}

extern "C" void kernel_launch(void* const* d_in, const int* in_sizes, int n_in,
                              void* d_out, int out_size, void* d_ws, size_t ws_size,
                              hipStream_t stream) {
    const float* x  = (const float*)d_in[0];   // [16,4096,256] fp32
    const float* ic = (const float*)d_in[1];   // [256,5] fp32
    const float* oc = (const float*)d_in[2];   // [256,256] fp32
    char* wb = (char*)d_ws;                    // 128 KB bf16 swizzled copy of W

    conv_w<<<64, 256, 0, stream>>>((const float4*)oc, wb);
    kan_fused<<<256, 512, 0, stream>>>(x, ic, wb, (float*)d_out);
}